// Round 6
// baseline (444.263 us; speedup 1.0000x reference)
//
#include <hip/hip_runtime.h>

typedef __attribute__((ext_vector_type(8))) short short8;
typedef __attribute__((ext_vector_type(4))) float f32x4;

#define IN_F 256
#define OUT_F 128

__device__ __forceinline__ float bf2f(unsigned int u16) {
    union { unsigned int i; float f; } v; v.i = u16 << 16; return v.f;
}
__device__ __forceinline__ unsigned short f2bf(float f) {
    union { float f; unsigned int i; } v; v.f = f;
    unsigned int u = v.i;
    return (unsigned short)((u + 0x7fffu + ((u >> 16) & 1u)) >> 16);
}

// ---------------- degree histogram ----------------
__global__ __launch_bounds__(256) void k_deg(const int* __restrict__ col, int* __restrict__ deg, int E) {
    int e = blockIdx.x * 256 + threadIdx.x;
    if (e < E) atomicAdd(&deg[col[e]], 1);
}

// ---------------- 3-kernel exclusive scan over deg (chunk = 1024) ----------------
__global__ __launch_bounds__(256) void k_scan1(const int* __restrict__ deg, int* __restrict__ bsum, int n) {
    __shared__ int sd[256];
    int t = threadIdx.x;
    int base = blockIdx.x * 1024 + t * 4;
    int s = 0;
#pragma unroll
    for (int i = 0; i < 4; i++) if (base + i < n) s += deg[base + i];
    sd[t] = s; __syncthreads();
    for (int off = 128; off > 0; off >>= 1) {
        if (t < off) sd[t] += sd[t + off];
        __syncthreads();
    }
    if (t == 0) bsum[blockIdx.x] = sd[0];
}

// one-block exclusive scan over block sums (nb <= 256)
__global__ __launch_bounds__(256) void k_scan2(int* __restrict__ bsum, int nb) {
    __shared__ int sd[256];
    int t = threadIdx.x;
    int v = (t < nb) ? bsum[t] : 0;
    sd[t] = v; __syncthreads();
    for (int off = 1; off < 256; off <<= 1) {
        int add = (t >= off) ? sd[t - off] : 0;
        __syncthreads();
        sd[t] += add;
        __syncthreads();
    }
    if (t < nb) bsum[t] = sd[t] - v;   // exclusive
}

// scan3 also emits dis = rsqrt(deg+1)
__global__ __launch_bounds__(256) void k_scan3(const int* __restrict__ deg, const int* __restrict__ bsum,
                                               int* __restrict__ offs, int* __restrict__ cursor,
                                               float* __restrict__ dis, int n) {
    __shared__ int sd[256];
    int t = threadIdx.x;
    int base = blockIdx.x * 1024 + t * 4;
    int v[4]; int s = 0;
#pragma unroll
    for (int i = 0; i < 4; i++) { v[i] = (base + i < n) ? deg[base + i] : 0; s += v[i]; }
    sd[t] = s; __syncthreads();
    for (int off = 1; off < 256; off <<= 1) {
        int add = (t >= off) ? sd[t - off] : 0;
        __syncthreads();
        sd[t] += add;
        __syncthreads();
    }
    int acc = sd[t] - s + bsum[blockIdx.x];
#pragma unroll
    for (int i = 0; i < 4; i++) {
        int idx = base + i;
        if (idx < n) {
            offs[idx] = acc; cursor[idx] = acc; acc += v[i];
            dis[idx] = rsqrtf((float)v[i] + 1.0f);
        }
    }
}

// ---------------- counting-sort scatter: CSR slot <- src_row (4B) ----------------
__global__ __launch_bounds__(256) void k_scatter(const int* __restrict__ row, const int* __restrict__ col,
                                                 int* __restrict__ cursor,
                                                 int* __restrict__ srci, int E) {
    int e = blockIdx.x * 256 + threadIdx.x;
    if (e < E) {
        int c = col[e];
        int pos = atomicAdd(&cursor[c], 1);
        srci[pos] = row[e];
    }
}

// ---------------- transpose+convert W f32 -> Wt[128][256] bf16 ; zero hb row N ----------------
__global__ __launch_bounds__(256) void k_transposeW(const float* __restrict__ W,
                                                    unsigned short* __restrict__ Wt,
                                                    unsigned short* __restrict__ hb, int N) {
    int idx = blockIdx.x * 256 + threadIdx.x;
    if (idx < IN_F * OUT_F) {
        int k = idx >> 7;       // 0..255
        int n = idx & 127;      // 0..127
        Wt[n * IN_F + k] = f2bf(W[idx]);
    }
    if (idx < OUT_F) hb[(size_t)N * OUT_F + idx] = 0;   // zero pad-row for agg tail lanes
}

// ---------------- GEMM: hb[r][:] = bf16( (bf16(x[r]) @ W + b) * dis[r] ) ----------------
// 32 rows/wave (two 16-row A-tiles share Wt fragments), register double-buffered prefetch.
__global__ __launch_bounds__(256) void k_gemm(const float* __restrict__ x,
                                              const unsigned short* __restrict__ Wt,
                                              const float* __restrict__ bias,
                                              const float* __restrict__ dis,
                                              unsigned short* __restrict__ hb, int nrows) {
    int wave = threadIdx.x >> 6;       // 0..3
    int lane = threadIdx.x & 63;
    int m = lane & 15;
    int quad = lane >> 4;

    int row0 = blockIdx.x * 128 + wave * 32;
    int nm1 = nrows - 1;
    int rA = row0 + m;      if (rA > nm1) rA = nm1;
    int rB = row0 + 16 + m; if (rB > nm1) rB = nm1;

    const float4* pa = (const float4*)(x + (size_t)rA * IN_F) + 2 * quad;
    const float4* pb = (const float4*)(x + (size_t)rB * IN_F) + 2 * quad;
    const short8* wf = (const short8*)Wt + (size_t)m * 32 + quad;   // frag(ct,i) = wf[ct*512 + 4*i]

    f32x4 acc[2][8];
#pragma unroll
    for (int t = 0; t < 2; t++)
#pragma unroll
        for (int ct = 0; ct < 8; ct++) acc[t][ct] = (f32x4){0.f, 0.f, 0.f, 0.f};

    float4 a0 = pa[0], a1 = pa[1];
    float4 b0 = pb[0], b1 = pb[1];
    short8 w[8];
#pragma unroll
    for (int ct = 0; ct < 8; ct++) w[ct] = wf[ct * 512];

#pragma unroll
    for (int i = 0; i < 8; i++) {
        float4 na0 = {}, na1 = {}, nb0 = {}, nb1 = {};
        short8 nw[8] = {};
        if (i < 7) {
            na0 = pa[8 * (i + 1)];     na1 = pa[8 * (i + 1) + 1];
            nb0 = pb[8 * (i + 1)];     nb1 = pb[8 * (i + 1) + 1];
#pragma unroll
            for (int ct = 0; ct < 8; ct++) nw[ct] = wf[ct * 512 + 4 * (i + 1)];
        }
        short8 af, bf;
        af[0] = (short)f2bf(a0.x); af[1] = (short)f2bf(a0.y);
        af[2] = (short)f2bf(a0.z); af[3] = (short)f2bf(a0.w);
        af[4] = (short)f2bf(a1.x); af[5] = (short)f2bf(a1.y);
        af[6] = (short)f2bf(a1.z); af[7] = (short)f2bf(a1.w);
        bf[0] = (short)f2bf(b0.x); bf[1] = (short)f2bf(b0.y);
        bf[2] = (short)f2bf(b0.z); bf[3] = (short)f2bf(b0.w);
        bf[4] = (short)f2bf(b1.x); bf[5] = (short)f2bf(b1.y);
        bf[6] = (short)f2bf(b1.z); bf[7] = (short)f2bf(b1.w);
#pragma unroll
        for (int ct = 0; ct < 8; ct++)
            acc[0][ct] = __builtin_amdgcn_mfma_f32_16x16x32_bf16(af, w[ct], acc[0][ct], 0, 0, 0);
#pragma unroll
        for (int ct = 0; ct < 8; ct++)
            acc[1][ct] = __builtin_amdgcn_mfma_f32_16x16x32_bf16(bf, w[ct], acc[1][ct], 0, 0, 0);
        a0 = na0; a1 = na1; b0 = nb0; b1 = nb1;
#pragma unroll
        for (int ct = 0; ct < 8; ct++) w[ct] = nw[ct];
    }

    // C/D: col = lane&15, row = quad*4 + reg
    float bv[8];
#pragma unroll
    for (int ct = 0; ct < 8; ct++) bv[ct] = bias[ct * 16 + m];

    int orow0 = blockIdx.x * 128 + wave * 32 + quad * 4;
#pragma unroll
    for (int t = 0; t < 2; t++) {
#pragma unroll
        for (int r = 0; r < 4; r++) {
            int orow = orow0 + t * 16 + r;
            if (orow < nrows) {
                float dr = dis[orow];
#pragma unroll
                for (int ct = 0; ct < 8; ct++)
                    hb[(size_t)orow * OUT_F + ct * 16 + m] = f2bf((acc[t][ct][r] + bv[ct]) * dr);
            }
        }
    }
}

// ---------------- aggregation: wave/node, coop src load + unroll-8 gathers, add-only ----------------
__global__ __launch_bounds__(256) void k_agg(const unsigned short* __restrict__ hb,
                                             const float* __restrict__ dis,
                                             const int* __restrict__ offs, const int* __restrict__ deg,
                                             const int* __restrict__ srci,
                                             float* __restrict__ out, int n) {
    int node = blockIdx.x * 4 + (threadIdx.x >> 6);
    if (node >= n) return;
    int lane = threadIdx.x & 63;

    unsigned int v = *(const unsigned int*)(hb + (size_t)node * OUT_F + lane * 2);
    float ax = bf2f(v & 0xffffu);   // self term: hb already scaled by dis[node]
    float ay = bf2f(v >> 16);

    int start = offs[node];
    int cnt = deg[node];

    for (int base = 0; base < cnt; base += 64) {
        int mm = cnt - base; if (mm > 64) mm = 64;
        int e = (lane < mm) ? srci[start + base + lane] : n;   // n = zero pad-row
        int mround = (mm + 7) & ~7;
        for (int j = 0; j < mround; j += 8) {
            int rr[8];
#pragma unroll
            for (int k = 0; k < 8; k++) rr[k] = __shfl(e, j + k);
            unsigned int w[8];
#pragma unroll
            for (int k = 0; k < 8; k++)
                w[k] = *(const unsigned int*)(hb + (size_t)rr[k] * OUT_F + lane * 2);
#pragma unroll
            for (int k = 0; k < 8; k++) {
                ax += bf2f(w[k] & 0xffffu);
                ay += bf2f(w[k] >> 16);
            }
        }
    }

    float di = dis[node];
    float2 o;
    o.x = fmaxf(ax * di, 0.f);
    o.y = fmaxf(ay * di, 0.f);
    *(float2*)(out + (size_t)node * OUT_F + lane * 2) = o;
}

static inline size_t alignup(size_t v, size_t a) { return (v + a - 1) & ~(a - 1); }

extern "C" void kernel_launch(void* const* d_in, const int* in_sizes, int n_in,
                              void* d_out, int out_size, void* d_ws, size_t ws_size,
                              hipStream_t stream) {
    const float* x  = (const float*)d_in[0];
    const int* ei   = (const int*)d_in[1];
    const float* W  = (const float*)d_in[2];
    const float* b  = (const float*)d_in[3];
    float* out      = (float*)d_out;

    const int N = in_sizes[0] / IN_F;      // 100000
    const int E = in_sizes[1] / 2;         // 1600000
    const int* rowp = ei;
    const int* colp = ei + E;

    // workspace carve (~34 MB total)
    char* ws = (char*)d_ws;
    size_t off = 0;
    int*   deg    = (int*)(ws + off);   off = alignup(off + (size_t)N * 4, 256);
    float* dis    = (float*)(ws + off); off = alignup(off + (size_t)N * 4, 256);
    int*   offs   = (int*)(ws + off);   off = alignup(off + (size_t)N * 4, 256);
    int*   cursor = (int*)(ws + off);   off = alignup(off + (size_t)N * 4, 256);
    int*   bsum   = (int*)(ws + off);   off = alignup(off + 4096, 256);
    unsigned short* Wt = (unsigned short*)(ws + off); off = alignup(off + (size_t)IN_F * OUT_F * 2, 256);
    int*   srci   = (int*)(ws + off);   off = alignup(off + (size_t)E * 4, 256);
    unsigned short* hb = (unsigned short*)(ws + off); off = alignup(off + (size_t)(N + 1) * OUT_F * 2, 256);

    (void)hipMemsetAsync(deg, 0, (size_t)N * 4, stream);

    k_deg<<<(E + 255) / 256, 256, 0, stream>>>(colp, deg, E);

    int nb = (N + 1023) / 1024;            // 98 <= 256
    k_scan1<<<nb, 256, 0, stream>>>(deg, bsum, N);
    k_scan2<<<1, 256, 0, stream>>>(bsum, nb);
    k_scan3<<<nb, 256, 0, stream>>>(deg, bsum, offs, cursor, dis, N);

    k_scatter<<<(E + 255) / 256, 256, 0, stream>>>(rowp, colp, cursor, srci, E);

    k_transposeW<<<(IN_F * OUT_F + 255) / 256, 256, 0, stream>>>(W, Wt, hb, N);
    k_gemm<<<(N + 127) / 128, 256, 0, stream>>>(x, Wt, b, dis, hb, N);

    k_agg<<<(N + 3) / 4, 256, 0, stream>>>(hb, dis, offs, deg, srci, out, N);
}

// Round 7
// 313.259 us; speedup vs baseline: 1.4182x; 1.4182x over previous
//
#include <hip/hip_runtime.h>

typedef __attribute__((ext_vector_type(8))) short short8;
typedef __attribute__((ext_vector_type(4))) float f32x4;

#define IN_F 256
#define OUT_F 128
#define NPB 256          // nodes per bucket (bucket = node >> 8)
#define MAXCAP 5120      // slots per bucket (mean 4092, +16 sigma)

__device__ __forceinline__ float bf2f(unsigned int u16) {
    union { unsigned int i; float f; } v; v.i = u16 << 16; return v.f;
}
__device__ __forceinline__ unsigned short f2bf(float f) {
    union { float f; unsigned int i; } v; v.f = f;
    unsigned int u = v.i;
    return (unsigned short)((u + 0x7fffu + ((u >> 16) & 1u)) >> 16);
}

// ---------------- pass 1: bucket-bin edges, packed (src<<8)|c_local ----------------
__global__ __launch_bounds__(256) void k_bin(const int* __restrict__ row, const int* __restrict__ col,
                                             int* __restrict__ bcur, int* __restrict__ ebuf,
                                             int E, int NBr, int chunk) {
    __shared__ int hist[512];
    __shared__ int cbase[512];
    int t = threadIdx.x;
    int e0 = blockIdx.x * chunk;
    int e1 = e0 + chunk; if (e1 > E) e1 = E;

    for (int i = t; i < NBr; i += 256) hist[i] = 0;
    __syncthreads();
    for (int i = e0 + t; i < e1; i += 256)
        atomicAdd(&hist[col[i] >> 8], 1);
    __syncthreads();
    for (int i = t; i < NBr; i += 256) {
        int h = hist[i];
        cbase[i] = h ? atomicAdd(&bcur[i], h) : 0;
    }
    __syncthreads();
    for (int i = t; i < NBr; i += 256) hist[i] = 0;
    __syncthreads();
    for (int i = e0 + t; i < e1; i += 256) {
        int c = col[i];
        int r = row[i];
        int b = c >> 8;
        int p = atomicAdd(&hist[b], 1) + cbase[b];
        ebuf[(size_t)b * MAXCAP + p] = (r << 8) | (c & 255);
    }
}

// ---------------- pass 2: per-bucket fine sort + deg/offs/dis, LDS atomics only ----------------
__global__ __launch_bounds__(256) void k_fine(const int* __restrict__ bcur, const int* __restrict__ ebuf,
                                              int* __restrict__ offs, int* __restrict__ deg,
                                              float* __restrict__ dis, int* __restrict__ srci, int N) {
    __shared__ int dl[256];
    __shared__ int sc[256];
    int b = blockIdx.x;
    int t = threadIdx.x;
    int count = bcur[b];
    const int* eb = ebuf + (size_t)b * MAXCAP;

    dl[t] = 0;
    __syncthreads();
    for (int i = t; i < count; i += 256)
        atomicAdd(&dl[eb[i] & 255], 1);
    __syncthreads();
    int myDeg = dl[t];
    // exclusive scan (Hillis-Steele)
    sc[t] = myDeg; __syncthreads();
    for (int off = 1; off < 256; off <<= 1) {
        int a = (t >= off) ? sc[t - off] : 0;
        __syncthreads();
        sc[t] += a;
        __syncthreads();
    }
    int excl = sc[t] - myDeg;
    int node = (b << 8) + t;
    int bbase = b * MAXCAP;
    if (node < N) {
        offs[node] = bbase + excl;
        deg[node] = myDeg;
        dis[node] = rsqrtf((float)myDeg + 1.0f);
    }
    dl[t] = excl;   // reuse as cursor
    __syncthreads();
    for (int i = t; i < count; i += 256) {
        int p = eb[i];
        int pos = atomicAdd(&dl[p & 255], 1);
        srci[bbase + pos] = p >> 8;    // stores within ~20 KB region -> L2-local
    }
}

// ---------------- transpose+convert W f32 -> Wt[128][256] bf16 ; zero hb row N ----------------
__global__ __launch_bounds__(256) void k_transposeW(const float* __restrict__ W,
                                                    unsigned short* __restrict__ Wt,
                                                    unsigned short* __restrict__ hb, int N) {
    int idx = blockIdx.x * 256 + threadIdx.x;
    if (idx < IN_F * OUT_F) {
        int k = idx >> 7;
        int n = idx & 127;
        Wt[n * IN_F + k] = f2bf(W[idx]);
    }
    if (idx < OUT_F) hb[(size_t)N * OUT_F + idx] = 0;
}

// ---------------- GEMM: hb[r][:] = bf16( (bf16(x[r]) @ W + b) * dis[r] ) ----------------
__global__ __launch_bounds__(256) void k_gemm(const float* __restrict__ x,
                                              const unsigned short* __restrict__ Wt,
                                              const float* __restrict__ bias,
                                              const float* __restrict__ dis,
                                              unsigned short* __restrict__ hb, int nrows) {
    int wave = threadIdx.x >> 6;
    int lane = threadIdx.x & 63;
    int m = lane & 15;
    int quad = lane >> 4;

    int row0 = blockIdx.x * 128 + wave * 32;
    int nm1 = nrows - 1;
    int rA = row0 + m;      if (rA > nm1) rA = nm1;
    int rB = row0 + 16 + m; if (rB > nm1) rB = nm1;

    const float4* pa = (const float4*)(x + (size_t)rA * IN_F) + 2 * quad;
    const float4* pb = (const float4*)(x + (size_t)rB * IN_F) + 2 * quad;
    const short8* wf = (const short8*)Wt + (size_t)m * 32 + quad;

    f32x4 acc[2][8];
#pragma unroll
    for (int t = 0; t < 2; t++)
#pragma unroll
        for (int ct = 0; ct < 8; ct++) acc[t][ct] = (f32x4){0.f, 0.f, 0.f, 0.f};

    float4 a0 = pa[0], a1 = pa[1];
    float4 b0 = pb[0], b1 = pb[1];
    short8 w[8];
#pragma unroll
    for (int ct = 0; ct < 8; ct++) w[ct] = wf[ct * 512];

#pragma unroll
    for (int i = 0; i < 8; i++) {
        float4 na0 = {}, na1 = {}, nb0 = {}, nb1 = {};
        short8 nw[8] = {};
        if (i < 7) {
            na0 = pa[8 * (i + 1)];     na1 = pa[8 * (i + 1) + 1];
            nb0 = pb[8 * (i + 1)];     nb1 = pb[8 * (i + 1) + 1];
#pragma unroll
            for (int ct = 0; ct < 8; ct++) nw[ct] = wf[ct * 512 + 4 * (i + 1)];
        }
        short8 af, bf;
        af[0] = (short)f2bf(a0.x); af[1] = (short)f2bf(a0.y);
        af[2] = (short)f2bf(a0.z); af[3] = (short)f2bf(a0.w);
        af[4] = (short)f2bf(a1.x); af[5] = (short)f2bf(a1.y);
        af[6] = (short)f2bf(a1.z); af[7] = (short)f2bf(a1.w);
        bf[0] = (short)f2bf(b0.x); bf[1] = (short)f2bf(b0.y);
        bf[2] = (short)f2bf(b0.z); bf[3] = (short)f2bf(b0.w);
        bf[4] = (short)f2bf(b1.x); bf[5] = (short)f2bf(b1.y);
        bf[6] = (short)f2bf(b1.z); bf[7] = (short)f2bf(b1.w);
#pragma unroll
        for (int ct = 0; ct < 8; ct++)
            acc[0][ct] = __builtin_amdgcn_mfma_f32_16x16x32_bf16(af, w[ct], acc[0][ct], 0, 0, 0);
#pragma unroll
        for (int ct = 0; ct < 8; ct++)
            acc[1][ct] = __builtin_amdgcn_mfma_f32_16x16x32_bf16(bf, w[ct], acc[1][ct], 0, 0, 0);
        a0 = na0; a1 = na1; b0 = nb0; b1 = nb1;
#pragma unroll
        for (int ct = 0; ct < 8; ct++) w[ct] = nw[ct];
    }

    float bv[8];
#pragma unroll
    for (int ct = 0; ct < 8; ct++) bv[ct] = bias[ct * 16 + m];

    int orow0 = blockIdx.x * 128 + wave * 32 + quad * 4;
#pragma unroll
    for (int t = 0; t < 2; t++) {
#pragma unroll
        for (int r = 0; r < 4; r++) {
            int orow = orow0 + t * 16 + r;
            if (orow < nrows) {
                float dr = dis[orow];
#pragma unroll
                for (int ct = 0; ct < 8; ct++)
                    hb[(size_t)orow * OUT_F + ct * 16 + m] = f2bf((acc[t][ct][r] + bv[ct]) * dr);
            }
        }
    }
}

// ---------------- aggregation: wave/node, coop src load + unroll-8 gathers, add-only ----------------
__global__ __launch_bounds__(256) void k_agg(const unsigned short* __restrict__ hb,
                                             const float* __restrict__ dis,
                                             const int* __restrict__ offs, const int* __restrict__ deg,
                                             const int* __restrict__ srci,
                                             float* __restrict__ out, int n) {
    int node = blockIdx.x * 4 + (threadIdx.x >> 6);
    if (node >= n) return;
    int lane = threadIdx.x & 63;

    unsigned int v = *(const unsigned int*)(hb + (size_t)node * OUT_F + lane * 2);
    float ax = bf2f(v & 0xffffu);
    float ay = bf2f(v >> 16);

    int start = offs[node];
    int cnt = deg[node];

    for (int base = 0; base < cnt; base += 64) {
        int mm = cnt - base; if (mm > 64) mm = 64;
        int e = (lane < mm) ? srci[start + base + lane] : n;
        int mround = (mm + 7) & ~7;
        for (int j = 0; j < mround; j += 8) {
            int rr[8];
#pragma unroll
            for (int k = 0; k < 8; k++) rr[k] = __shfl(e, j + k);
            unsigned int w[8];
#pragma unroll
            for (int k = 0; k < 8; k++)
                w[k] = *(const unsigned int*)(hb + (size_t)rr[k] * OUT_F + lane * 2);
#pragma unroll
            for (int k = 0; k < 8; k++) {
                ax += bf2f(w[k] & 0xffffu);
                ay += bf2f(w[k] >> 16);
            }
        }
    }

    float di = dis[node];
    float2 o;
    o.x = fmaxf(ax * di, 0.f);
    o.y = fmaxf(ay * di, 0.f);
    *(float2*)(out + (size_t)node * OUT_F + lane * 2) = o;
}

static inline size_t alignup(size_t v, size_t a) { return (v + a - 1) & ~(a - 1); }

extern "C" void kernel_launch(void* const* d_in, const int* in_sizes, int n_in,
                              void* d_out, int out_size, void* d_ws, size_t ws_size,
                              hipStream_t stream) {
    const float* x  = (const float*)d_in[0];
    const int* ei   = (const int*)d_in[1];
    const float* W  = (const float*)d_in[2];
    const float* b  = (const float*)d_in[3];
    float* out      = (float*)d_out;

    const int N = in_sizes[0] / IN_F;      // 100000
    const int E = in_sizes[1] / 2;         // 1600000
    const int* rowp = ei;
    const int* colp = ei + E;

    const int NBr = (N + NPB - 1) / NPB;   // 391 buckets (<= 512)

    // workspace carve (~44 MB total)
    char* ws = (char*)d_ws;
    size_t off = 0;
    int*   bcur   = (int*)(ws + off);   off = alignup(off + (size_t)NBr * 4, 256);
    int*   deg    = (int*)(ws + off);   off = alignup(off + (size_t)N * 4, 256);
    float* dis    = (float*)(ws + off); off = alignup(off + (size_t)N * 4, 256);
    int*   offs   = (int*)(ws + off);   off = alignup(off + (size_t)N * 4, 256);
    unsigned short* Wt = (unsigned short*)(ws + off); off = alignup(off + (size_t)IN_F * OUT_F * 2, 256);
    int*   ebuf   = (int*)(ws + off);   off = alignup(off + (size_t)NBr * MAXCAP * 4, 256);
    int*   srci   = (int*)(ws + off);   off = alignup(off + (size_t)NBr * MAXCAP * 4, 256);
    unsigned short* hb = (unsigned short*)(ws + off); off = alignup(off + (size_t)(N + 1) * OUT_F * 2, 256);

    (void)hipMemsetAsync(bcur, 0, (size_t)NBr * 4, stream);

    int chunk = (E + 511) / 512;           // 3125 edges/block
    k_bin<<<512, 256, 0, stream>>>(rowp, colp, bcur, ebuf, E, NBr, chunk);
    k_fine<<<NBr, 256, 0, stream>>>(bcur, ebuf, offs, deg, dis, srci, N);

    k_transposeW<<<(IN_F * OUT_F + 255) / 256, 256, 0, stream>>>(W, Wt, hb, N);
    k_gemm<<<(N + 127) / 128, 256, 0, stream>>>(x, Wt, b, dis, hb, N);

    k_agg<<<(N + 3) / 4, 256, 0, stream>>>(hb, dis, offs, deg, srci, out, N);
}